// Round 6
// baseline (98.084 us; speedup 1.0000x reference)
//
#include <hip/hip_runtime.h>
#include <hip/hip_bf16.h>

// ---------------------------------------------------------------------------
// advantage = -0.5 * || T(flat) @ (actions-best) ||^2 per row, where
// flat = logits @ W^T + b, T = lower-tri scatter with squared diagonal.
// Round 6: no-LDS, no-barrier K-loop. Per wave: 9 W-frags (L2-hot, prepacked)
// + 4 A-frags (f32 HBM) loaded straight to registers each step, distance-1
// prefetch by program order (loads issued after last MFMA use). LDS only for
// the epilogue (flat[128][1216B] = 152 KB, 1 block/CU).
// ---------------------------------------------------------------------------

typedef __attribute__((ext_vector_type(8))) __bf16 bf16x8;
typedef __attribute__((ext_vector_type(4))) float f32x4;

__device__ __forceinline__ unsigned short f2b(float x) {
  unsigned u = __builtin_bit_cast(unsigned, x);
  u += 0x7fffu + ((u >> 16) & 1u);     // RNE; inputs are finite
  return (unsigned short)(u >> 16);
}
__device__ __forceinline__ float b2f(unsigned short h) {
  unsigned u = ((unsigned)h) << 16;
  return __builtin_bit_cast(float, u);
}

#define NFRAG 34                       // 544 padded cols / 16 (WP layout)
#define WK_BYTES (NFRAG * 1024)        // 34816 B per BK=32 step in WP
#define FL_STRIDE 1216                 // flat row stride (bytes)
#define PL_OFF (128 * FL_STRIDE)       // 155648
#define SMEM_BYTES (PL_OFF + 2048)     // 157696 <= 163840 (1 block/CU)

// --- prep: W [528][512] f32 -> fragment-linear bf16, padded to 544 rows ----
// WP[k16][nf][lane][j] = bf16(W[nf*16+(lane&15)][k16*32+(lane>>4)*8+j])
__global__ void prep_wp(const float* __restrict__ W, unsigned short* __restrict__ WP) {
  int t = blockIdx.x * 256 + threadIdx.x;   // [0, 34816)
  int lane = t & 63;
  int u = t >> 6;                            // [0, 544)
  int nf = u % NFRAG;
  int k16 = u / NFRAG;                       // [0, 16)
  int n = nf * 16 + (lane & 15);
  int k0 = k16 * 32 + (lane >> 4) * 8;
  unsigned short h[8];
  if (n < 528) {
    const float* src = W + (size_t)n * 512 + k0;
#pragma unroll
    for (int j = 0; j < 8; ++j) h[j] = f2b(src[j]);
  } else {
#pragma unroll
    for (int j = 0; j < 8; ++j) h[j] = 0;
  }
  uint4 p;
  p.x = (unsigned)h[0] | ((unsigned)h[1] << 16);
  p.y = (unsigned)h[2] | ((unsigned)h[3] << 16);
  p.z = (unsigned)h[4] | ((unsigned)h[5] << 16);
  p.w = (unsigned)h[6] | ((unsigned)h[7] << 16);
  *(uint4*)(WP + (size_t)t * 8) = p;
}

// --- epilogue worker: one lane per row, i in {IT, IT+4, ..., IT+28} --------
template <int IT>
__device__ __forceinline__ float epi_partial(const char* smem,
                                             const float* __restrict__ actions,
                                             const float* __restrict__ best,
                                             int growg, int lrow) {
  float d[32];
  const float* ap = actions + (size_t)growg * 32;
  const float* bp = best + (size_t)growg * 32;
#pragma unroll
  for (int q = 0; q < 8; ++q) {
    float4 av = *(const float4*)(ap + q * 4);
    float4 bv = *(const float4*)(bp + q * 4);
    d[q * 4 + 0] = av.x - bv.x;
    d[q * 4 + 1] = av.y - bv.y;
    d[q * 4 + 2] = av.z - bv.z;
    d[q * 4 + 3] = av.w - bv.w;
  }
  const char* frow = smem + lrow * FL_STRIDE;
  const int swz = (lrow & 7) << 4;
  float ssum = 0.f;
#pragma unroll
  for (int ii = 0; ii < 8; ++ii) {
    const int i = IT + ii * 4;          // compile-time
    const int tri2 = i * (i + 1);       // byte offset of row-i start in flat
    const int s0 = tri2 >> 4;
    const int s1 = (tri2 + 2 * i) >> 4;
    float vec = 0.f;
#pragma unroll
    for (int s = s0; s <= s1; ++s) {
      uint4 w = *(const uint4*)(frow + ((s * 16) ^ swz));
      const unsigned* wp = (const unsigned*)&w;
#pragma unroll
      for (int e = 0; e < 8; ++e) {
        const int j = s * 8 + e - (tri2 >> 1);   // compile-time
        if (j < 0 || j > i) continue;
        unsigned short h = (e & 1) ? (unsigned short)(wp[e >> 1] >> 16)
                                   : (unsigned short)(wp[e >> 1] & 0xffffu);
        float v = b2f(h);
        if (j == i) vec += v * v * d[i];         // squared diagonal
        else        vec += v * d[j];
      }
    }
    ssum += vec * vec;
  }
  return ssum;
}

// --- main fused kernel ------------------------------------------------------
__global__ void __launch_bounds__(512, 2)
adv_kernel(const float* __restrict__ logits,
           const float* __restrict__ best,
           const float* __restrict__ actions,
           const float* __restrict__ bvec,
           const unsigned short* __restrict__ WP,
           float* __restrict__ out) {
  extern __shared__ char smem[];
  const int tid  = threadIdx.x;
  const int l    = tid & 63;
  const int wid  = tid >> 6;               // 8 waves: 2 M-halves x 4 N-cols
  const int half = wid >> 2;
  const int wc   = wid & 3;
  const int lr   = l & 15;
  const int lg   = l >> 4;
  const int start = wc * 8 + (wc > 0 ? 1 : 0);   // 0,9,17,25 (17,25 dup'd)
  const int brow = blockIdx.x * 128;

  f32x4 acc[4][9];
  {
    f32x4 zero = {0.f, 0.f, 0.f, 0.f};
#pragma unroll
    for (int m = 0; m < 4; ++m)
#pragma unroll
      for (int n = 0; n < 9; ++n) acc[m][n] = zero;
  }

  // per-lane global bases
  const char* wlane = (const char*)WP + (size_t)start * 1024 + (size_t)l * 16;
  const float* ag0 = logits + (size_t)(brow + half * 64 + 0 * 16 + lr) * 512 + lg * 8;
  const float* ag1 = logits + (size_t)(brow + half * 64 + 1 * 16 + lr) * 512 + lg * 8;
  const float* ag2 = logits + (size_t)(brow + half * 64 + 2 * 16 + lr) * 512 + lg * 8;
  const float* ag3 = logits + (size_t)(brow + half * 64 + 3 * 16 + lr) * 512 + lg * 8;

  uint4 wreg[9];                  // current W fragments (bf16-packed)
  float4 araw[4][2];              // current A fragment source (f32)

#define LOADW(t)                                                                \
  {                                                                             \
    const char* p = wlane + (size_t)(t) * WK_BYTES;                             \
    _Pragma("unroll")                                                           \
    for (int n = 0; n < 9; ++n) wreg[n] = *(const uint4*)(p + n * 1024);        \
  }
#define LOADA(t)                                                                \
  {                                                                             \
    araw[0][0] = *(const float4*)(ag0 + (t) * 32);                              \
    araw[0][1] = *(const float4*)(ag0 + (t) * 32 + 4);                          \
    araw[1][0] = *(const float4*)(ag1 + (t) * 32);                              \
    araw[1][1] = *(const float4*)(ag1 + (t) * 32 + 4);                          \
    araw[2][0] = *(const float4*)(ag2 + (t) * 32);                              \
    araw[2][1] = *(const float4*)(ag2 + (t) * 32 + 4);                          \
    araw[3][0] = *(const float4*)(ag3 + (t) * 32);                              \
    araw[3][1] = *(const float4*)(ag3 + (t) * 32 + 4);                          \
  }

  LOADW(0)
  LOADA(0)

  for (int t = 0; t < 16; ++t) {
    // pack A f32 -> bf16x8 (compiler inserts per-reg waitcnt for araw)
    bf16x8 a[4];
#pragma unroll
    for (int m = 0; m < 4; ++m) {
      bf16x8 af;
      af[0] = (__bf16)araw[m][0].x; af[1] = (__bf16)araw[m][0].y;
      af[2] = (__bf16)araw[m][0].z; af[3] = (__bf16)araw[m][0].w;
      af[4] = (__bf16)araw[m][1].x; af[5] = (__bf16)araw[m][1].y;
      af[6] = (__bf16)araw[m][1].z; af[7] = (__bf16)araw[m][1].w;
      a[m] = af;
    }
    __builtin_amdgcn_s_setprio(1);
#pragma unroll
    for (int n = 0; n < 9; ++n) {
      bf16x8 w = __builtin_bit_cast(bf16x8, wreg[n]);
#pragma unroll
      for (int m = 0; m < 4; ++m)
        acc[m][n] = __builtin_amdgcn_mfma_f32_16x16x32_bf16(a[m], w, acc[m][n], 0, 0, 0);
    }
    __builtin_amdgcn_s_setprio(0);
    // distance-1 prefetch: issued after the last MFMA reads wreg/araw (WAR by
    // program order); in flight across the back-edge, awaited at next pack/use.
    if (t < 15) {
      LOADW(t + 1)
      LOADA(t + 1)
    }
  }

  // ---- epilogue: flat(+bias) -> swizzled bf16 LDS [128][FL_STRIDE] ---------
#pragma unroll
  for (int n = 0; n < 9; ++n) {
    int nf = start + n;
    if (nf >= 33) continue;              // frag 33 is pure padding
    int f = nf * 16 + lr;                // < 528
    float bb = bvec[f];
#pragma unroll
    for (int m = 0; m < 4; ++m)
#pragma unroll
      for (int r = 0; r < 4; ++r) {
        int row = half * 64 + m * 16 + lg * 4 + r;  // C/D: col=lane&15, row=(lane>>4)*4+reg
        int byte = row * FL_STRIDE + ((f * 2) ^ ((row & 7) << 4));
        *(unsigned short*)(smem + byte) = f2b(acc[m][n][r] + bb);
      }
  }
  __syncthreads();

  // ---- tril matvec: 4 waves per 64-row half, one lane per row, IT = wc -----
  {
    const int lrow = half * 64 + l;           // LDS flat row
    const int growg = brow + lrow;            // global row
    float ssum;
    switch (wc) {
      case 0:  ssum = epi_partial<0>(smem, actions, best, growg, lrow); break;
      case 1:  ssum = epi_partial<1>(smem, actions, best, growg, lrow); break;
      case 2:  ssum = epi_partial<2>(smem, actions, best, growg, lrow); break;
      default: ssum = epi_partial<3>(smem, actions, best, growg, lrow); break;
    }
    ((float*)(smem + PL_OFF))[lrow * 4 + wc] = ssum;
  }
  __syncthreads();
  if (tid < 128) {
    f32x4 p4 = *(const f32x4*)(smem + PL_OFF + tid * 16);
    out[brow + tid] = -0.5f * (p4[0] + p4[1] + p4[2] + p4[3]);
  }
}

extern "C" void kernel_launch(void* const* d_in, const int* in_sizes, int n_in,
                              void* d_out, int out_size, void* d_ws, size_t ws_size,
                              hipStream_t stream) {
  const float* logits  = (const float*)d_in[0];
  const float* best    = (const float*)d_in[1];
  const float* actions = (const float*)d_in[2];
  const float* W       = (const float*)d_in[3];
  const float* bvec    = (const float*)d_in[4];
  float* out = (float*)d_out;
  unsigned short* WP = (unsigned short*)d_ws;   // needs 557056 B

  hipLaunchKernelGGL(prep_wp, dim3(136), dim3(256), 0, stream, W, WP);
  int M = in_sizes[0] / 512;                    // 65536 rows
  hipLaunchKernelGGL(adv_kernel, dim3(M / 128), dim3(512), SMEM_BYTES, stream,
                     logits, best, actions, bvec, WP, out);
}